// Round 10
// baseline (1127.670 us; speedup 1.0000x reference)
//
#include <hip/hip_runtime.h>
#include <hip/hip_bf16.h>
#include <stdint.h>

#define N_NODES 50000
#define N_EDGES 400000
#define F_IN 256
#define HID 1024
#define F_MID 512
#define F_OUT 10
#define MP 50176      // N_NODES padded to 128*392
#define CH 25088      // layer-2 M-chunk (128*196)

typedef _Float16 f16;
typedef _Float16 f16x4 __attribute__((ext_vector_type(4)));
typedef _Float16 f16x8 __attribute__((ext_vector_type(8)));
typedef float f32x4 __attribute__((ext_vector_type(4)));

__device__ static inline void async_load16(const void* g, void* l) {
    __builtin_amdgcn_global_load_lds(
        (const __attribute__((address_space(1))) unsigned int*)(uintptr_t)g,
        (__attribute__((address_space(3))) unsigned int*)(uintptr_t)l, 16, 0, 0);
}

// ---------------- utility ----------------
__global__ __launch_bounds__(256) void zero_i32(int* __restrict__ p, int n) {
    int i = blockIdx.x * 256 + threadIdx.x;
    if (i < n) p[i] = 0;
}

__global__ __launch_bounds__(256) void probe_kernel(float* __restrict__ out, int n, float val) {
    int i = blockIdx.x * 256 + threadIdx.x;
    if (i < n) out[i] = (i == 0) ? val : 0.f;
}

// ---------------- CSR build ----------------
__global__ __launch_bounds__(256) void hist_kernel(const int* __restrict__ dst, int* __restrict__ rowptr) {
    int e = blockIdx.x * 256 + threadIdx.x;
    if (e < N_EDGES) atomicAdd(&rowptr[dst[e] + 1], 1);
}

__global__ __launch_bounds__(256) void scan1_kernel(int* __restrict__ data, int* __restrict__ bsums, int n) {
    __shared__ int tmp[256];
    int idx = blockIdx.x * 256 + threadIdx.x;
    int v = (idx < n) ? data[idx] : 0;
    tmp[threadIdx.x] = v;
    __syncthreads();
    for (int o = 1; o < 256; o <<= 1) {
        int t = (threadIdx.x >= o) ? tmp[threadIdx.x - o] : 0;
        __syncthreads();
        tmp[threadIdx.x] += t;
        __syncthreads();
    }
    if (idx < n) data[idx] = tmp[threadIdx.x];
    if (threadIdx.x == 255) bsums[blockIdx.x] = tmp[255];
}

__global__ __launch_bounds__(256) void scan2_kernel(int* __restrict__ bsums, int nb) {
    __shared__ int tmp[256];
    int t = threadIdx.x;
    int v = (t < nb) ? bsums[t] : 0;
    tmp[t] = v;
    __syncthreads();
    for (int o = 1; o < 256; o <<= 1) {
        int u = (t >= o) ? tmp[t - o] : 0;
        __syncthreads();
        tmp[t] += u;
        __syncthreads();
    }
    if (t < nb) bsums[t] = tmp[t] - v;  // exclusive block offsets
}

__global__ __launch_bounds__(256) void scan3_kernel(int* __restrict__ data, const int* __restrict__ bsums, int n) {
    int idx = blockIdx.x * 256 + threadIdx.x;
    if (idx < n) data[idx] += bsums[blockIdx.x];
}

__global__ __launch_bounds__(256) void fill_kernel(const int* __restrict__ src, const int* __restrict__ dst,
                                                   const int* __restrict__ rowptr, int* __restrict__ cursor,
                                                   int* __restrict__ col) {
    int e = blockIdx.x * 256 + threadIdx.x;
    if (e < N_EDGES) {
        int d = dst[e];
        int p = atomicAdd(&cursor[d], 1);
        col[rowptr[d] + p] = src[e];
    }
}

// ---------------- batched weight transpose fp32 [K][N] -> fp16 [N][K] ----------------
__global__ __launch_bounds__(256) void transw_all(const float* __restrict__ Wa, f16* __restrict__ Ta,
                                                  const float* __restrict__ Wb, f16* __restrict__ Tb,
                                                  const float* __restrict__ Wc, f16* __restrict__ Tc,
                                                  const float* __restrict__ Wd, f16* __restrict__ Td,
                                                  const float* __restrict__ We, f16* __restrict__ Te) {
    const float* W; f16* T; int N, K;
    switch (blockIdx.z) {
        case 0: W = Wa; T = Ta; N = HID;   K = F_IN; break;
        case 1: W = Wb; T = Tb; N = HID;   K = F_IN; break;
        case 2: W = Wc; T = Tc; N = HID;   K = HID;  break;
        case 3: W = Wd; T = Td; N = HID;   K = HID;  break;
        default:W = We; T = Te; N = F_MID; K = HID;  break;
    }
    int n = blockIdx.x * 256 + threadIdx.x;
    int k0 = blockIdx.y * 8;
    if (n >= N || k0 >= K) return;
    f16x8 o;
#pragma unroll
    for (int j = 0; j < 8; j++) o[j] = (f16)W[(size_t)(k0 + j) * N + n];
    *(f16x8*)(T + (size_t)n * K + k0) = o;
}

// ---------------- x fp32 -> fp16 (covers pad rows with zeros) ----------------
__global__ __launch_bounds__(256) void convx_kernel(const float* __restrict__ x, f16* __restrict__ xh) {
    int idx = blockIdx.x * 256 + threadIdx.x;  // MP*64 float4 units
    if (idx < N_NODES * 64) {
        float4 v = ((const float4*)x)[idx];
        f16x4 o;
        o[0] = (f16)v.x; o[1] = (f16)v.y; o[2] = (f16)v.z; o[3] = (f16)v.w;
        *(f16x4*)(xh + (size_t)idx * 4) = o;
    } else {
        *(f16x4*)(xh + (size_t)idx * 4) = (f16x4){};
    }
}

// ---------------- mean aggregation, layer 1 (barrier-free; zero-fills pad rows) ----------------
__global__ __launch_bounds__(256) void agg1_kernel(const f16* __restrict__ xh, const int* __restrict__ rowptr,
                                                   const int* __restrict__ col, f16* __restrict__ agg1h) {
    const int node = blockIdx.x * 4 + (threadIdx.x >> 6);
    const int t = threadIdx.x & 63;
    if (node >= N_NODES) {
        *(f16x4*)(agg1h + (size_t)node * F_IN + t * 4) = (f16x4){};
        return;
    }
    const int beg = rowptr[node], end = rowptr[node + 1];
    float a0 = 0.f, a1 = 0.f, a2 = 0.f, a3 = 0.f;
    int e = beg;
    for (; e + 3 < end; e += 4) {
        int c0 = col[e], c1 = col[e + 1], c2 = col[e + 2], c3 = col[e + 3];
        f16x4 v0 = *(const f16x4*)(xh + (size_t)c0 * F_IN + t * 4);
        f16x4 v1 = *(const f16x4*)(xh + (size_t)c1 * F_IN + t * 4);
        f16x4 v2 = *(const f16x4*)(xh + (size_t)c2 * F_IN + t * 4);
        f16x4 v3 = *(const f16x4*)(xh + (size_t)c3 * F_IN + t * 4);
        a0 += (float)v0[0] + (float)v1[0] + (float)v2[0] + (float)v3[0];
        a1 += (float)v0[1] + (float)v1[1] + (float)v2[1] + (float)v3[1];
        a2 += (float)v0[2] + (float)v1[2] + (float)v2[2] + (float)v3[2];
        a3 += (float)v0[3] + (float)v1[3] + (float)v2[3] + (float)v3[3];
    }
    for (; e < end; ++e) {
        f16x4 v = *(const f16x4*)(xh + (size_t)col[e] * F_IN + t * 4);
        a0 += (float)v[0]; a1 += (float)v[1]; a2 += (float)v[2]; a3 += (float)v[3];
    }
    int deg = end - beg;
    float inv = 1.f / (float)(deg > 1 ? deg : 1);
    f16x4 o;
    o[0] = (f16)(a0 * inv); o[1] = (f16)(a1 * inv);
    o[2] = (f16)(a2 * inv); o[3] = (f16)(a3 * inv);
    *(f16x4*)(agg1h + (size_t)node * F_IN + t * 4) = o;
}

// ---------------- mean aggregation, layer 2 (barrier-free; zero-fills pad rows) ----------------
__global__ __launch_bounds__(256) void agg2_kernel(const f16* __restrict__ h1, const int* __restrict__ rowptr,
                                                   const int* __restrict__ col, f16* __restrict__ aggbuf,
                                                   int m_base, int real) {
    const int local = blockIdx.x * 2 + (threadIdx.x >> 7);
    const int t = threadIdx.x & 127;
    if (local >= real) {
        *(f16x8*)(aggbuf + (size_t)local * HID + t * 8) = (f16x8){};
        return;
    }
    const int node = m_base + local;
    const int beg = rowptr[node], end = rowptr[node + 1];
    float a[8];
#pragma unroll
    for (int j = 0; j < 8; j++) a[j] = 0.f;
    int e = beg;
    for (; e + 3 < end; e += 4) {
        int c0 = col[e], c1 = col[e + 1], c2 = col[e + 2], c3 = col[e + 3];
        f16x8 v0 = *(const f16x8*)(h1 + (size_t)c0 * HID + t * 8);
        f16x8 v1 = *(const f16x8*)(h1 + (size_t)c1 * HID + t * 8);
        f16x8 v2 = *(const f16x8*)(h1 + (size_t)c2 * HID + t * 8);
        f16x8 v3 = *(const f16x8*)(h1 + (size_t)c3 * HID + t * 8);
#pragma unroll
        for (int j = 0; j < 8; j++)
            a[j] += (float)v0[j] + (float)v1[j] + (float)v2[j] + (float)v3[j];
    }
    for (; e < end; ++e) {
        f16x8 v = *(const f16x8*)(h1 + (size_t)col[e] * HID + t * 8);
#pragma unroll
        for (int j = 0; j < 8; j++) a[j] += (float)v[j];
    }
    int deg = end - beg;
    float inv = 1.f / (float)(deg > 1 ? deg : 1);
    f16x8 o;
#pragma unroll
    for (int j = 0; j < 8; j++) o[j] = (f16)(a[j] * inv);
    *(f16x8*)(aggbuf + (size_t)local * HID + t * 8) = o;
}

// ---------------- 128x256 BK=32 two-source MFMA GEMM, 2 blocks/CU (TLP overlap) ----------------
// Rationale (rounds 2-8 post-mortem): at 1 block/CU, every intra-block schedule measured
// sum-of-pipes (MFMA 2170 + LDS 2870 cyc/K-tile = measured 4840) — barrier-locked waves of a
// single block alternate LDS-burst/MFMA-burst. Round-0's 2-blocks/CU gemm2 ran at 80-100% of
// its LDS roofline: the sibling block's waves fill the other pipe (m114). This kernel restores
// that regime: 256 threads = 4 waves (2M x 2N), wave tile 64x128; LDS 48 KB -> 2 blocks/CU.
// Simple 2-barrier K-step (round-0-proven): syncthreads (compiler inserts full vmcnt/lgkm
// drain) covers stage(t); stage(t+1) flies under reads+MFMA of t. 32 MFMAs/K-step, all
// distinct accs (no dep stalls).
// *** ROUND-9 BUG FIX: staging must cover A 8KB + B 16KB = 24KB/K-step = 6 x 16B loads per
// *** thread (round 9 issued 3 -> half of A/B uninitialized -> NaN). Slot map property:
// *** u -> u+256 leaves (L&7), chunk unchanged and adds +64 to the row, so the extra loads
// *** are src+64*KK at dest+4096B.
// LDS layout: paired rows — rows 2L,2L+1 share a 128B line; slot(u): L=u>>3, v=(u&7)^(L&7),
// row=2L+(v>>2), chunk=(v&3)*8 f16. Read side: slot s=(q+(r16&1)*4)^(r16>>1) — each 8-lane
// read group hits 8 distinct 16B slots (conflict-free); global_load_lds dest stays LINEAR,
// source pre-permuted with the inverse map (both-sides rule).
// XCD-chunked bijective remap + N-fastest decode (keeps FETCH ~ideal, round-4-verified).
__global__ __launch_bounds__(256, 2) void gemm128_f16(const f16* __restrict__ A0, const f16* __restrict__ B0, int K0,
                                                      const f16* __restrict__ A1, const f16* __restrict__ B1, int K1,
                                                      f16* __restrict__ C, const float* __restrict__ bias,
                                                      float* __restrict__ statS, int statBase, int N, int lnN) {
    __shared__ __align__(16) f16 smem[24576];  // 48 KiB: 2 buf x (A 4096 | B 8192) f16
    const int tid = threadIdx.x;
    const int wid = tid >> 6, lane = tid & 63;
    const int wr = wid >> 1, wc = wid & 1;
    const int r16 = lane & 15, q = lane >> 4;
    const int nwg = (int)gridDim.x;
    const int bid = (int)blockIdx.x;
    const int wgid = (bid & 7) * (nwg >> 3) + (bid >> 3);  // XCD-chunked (nwg%8==0)
    const int mt = wgid >> lnN;
    const int nt = wgid & ((1 << lnN) - 1);                // N fastest within chunk
    const int m0 = mt << 7;
    const int n0 = nt << 8;
    const int T0 = K0 >> 5;
    const int T = T0 + (K1 >> 5);

    // stage-source permutation (inverse of read-side slot map), from slot u = tid:
    const int LA = tid >> 3;
    const int vA = (tid & 7) ^ (LA & 7);
    const int rS = 2 * LA + (vA >> 2);          // base row 0-63; +64/tier for higher slots
    const int cS = (vA & 3) * 8;                // f16 offset within 32-f16 row

    // 6 async 16B loads/thread/K-step: A rows {rS, rS+64}; B rows {rS, +64, +128, +192}.
#define STG(t, bi) do {                                                                       \
        const f16* Ab; const f16* Bb; int kk, KK;                                             \
        if ((t) < T0) { Ab = A0; Bb = B0; kk = (t) << 5;        KK = K0; }                    \
        else          { Ab = A1; Bb = B1; kk = ((t) - T0) << 5; KK = K1; }                    \
        f16* base = smem + (bi) * 12288;                                                      \
        const f16* as = Ab + (size_t)(m0 + rS) * KK + kk + cS;                                \
        const f16* bs = Bb + (size_t)(n0 + rS) * KK + kk + cS;                                \
        const size_t st = (size_t)64 * KK;                                                    \
        async_load16(as,            base + tid * 8);                                          \
        async_load16(as + st,       base + 2048 + tid * 8);                                   \
        async_load16(bs,            base + 4096 + tid * 8);                                   \
        async_load16(bs + st,       base + 6144 + tid * 8);                                   \
        async_load16(bs + 2 * st,   base + 8192 + tid * 8);                                   \
        async_load16(bs + 3 * st,   base + 10240 + tid * 8);                                  \
    } while (0)

    f32x4 acc[4][8];  // [mf][nf]: rows wr*64+mf*16, cols wc*128+nf*16
#pragma unroll
    for (int i = 0; i < 4; i++)
#pragma unroll
        for (int j = 0; j < 8; j++) acc[i][j] = (f32x4){0.f, 0.f, 0.f, 0.f};

    // read-side addressing: slot s is lane-constant (row bases are multiples of 16)
    const int s = (q + (r16 & 1) * 4) ^ (r16 >> 1);
    const int pb = (r16 >> 1) * 64 + s * 8;         // f16 units within section
    const int aoff = wr * 2048 + pb;                // + mf*512
    const int boff = 4096 + wc * 4096 + pb;         // + nf*512

    STG(0, 0);
    for (int t = 0; t < T; ++t) {
        const int bi = t & 1;
        __syncthreads();                    // full drain (compiler: vmcnt0+lgkm0) -> stage(t) in
        if (t + 1 < T) STG(t + 1, bi ^ 1);  // flies under reads+MFMA below
        const f16* sb = smem + bi * 12288;
        f16x8 af[4], bf[8];
#pragma unroll
        for (int mf = 0; mf < 4; mf++) af[mf] = *(const f16x8*)(sb + aoff + mf * 512);
#pragma unroll
        for (int nf = 0; nf < 8; nf++) bf[nf] = *(const f16x8*)(sb + boff + nf * 512);
#pragma unroll
        for (int nf = 0; nf < 8; nf++)
#pragma unroll
            for (int mf = 0; mf < 4; mf++)
                acc[mf][nf] = __builtin_amdgcn_mfma_f32_16x16x32_f16(af[mf], bf[nf], acc[mf][nf], 0, 0, 0);
    }
#undef STG

    // epilogue: C = acc (+bias, relu). M multiple of 128 (padded, no guard).
#pragma unroll
    for (int mf = 0; mf < 4; mf++)
#pragma unroll
        for (int rr = 0; rr < 4; rr++) {
            const int grow = m0 + wr * 64 + mf * 16 + q * 4 + rr;
            f16* crow = C + (size_t)grow * N + n0 + wc * 128;
#pragma unroll
            for (int nf = 0; nf < 8; nf++) {
                const int col = nf * 16 + r16;
                float v = acc[mf][nf][rr];
                if (bias) { v += bias[n0 + wc * 128 + col]; v = v > 0.f ? v : 0.f; }
                crow[col] = (f16)v;
            }
        }

    // fused BN stats: per-block column sums of its 128x256 C-tile -> statS[statBase+mt][2][1024]
    if (statS) {
        __syncthreads();  // all waves done with LDS tile reads
        float* ps = (float*)smem;        // 512 floats
        float* pq = ps + 512;
#pragma unroll
        for (int nf = 0; nf < 8; nf++) {
            float sv = 0.f, qv = 0.f;
#pragma unroll
            for (int mf = 0; mf < 4; mf++)
#pragma unroll
                for (int rr = 0; rr < 4; rr++) { float v = acc[mf][nf][rr]; sv += v; qv += v * v; }
            sv += __shfl_xor(sv, 16); sv += __shfl_xor(sv, 32);
            qv += __shfl_xor(qv, 16); qv += __shfl_xor(qv, 32);
            if (q == 0) { ps[wid * 128 + nf * 16 + r16] = sv; pq[wid * 128 + nf * 16 + r16] = qv; }
        }
        __syncthreads();
        // col c of 256-wide tile: wave-col wc=c>>7 -> waves {wc, 2+wc} (wr 0,1)
        {
            const int c = tid;
            const int wcc = c >> 7, rest = c & 127;
            float S = ps[wcc * 128 + rest] + ps[(2 + wcc) * 128 + rest];
            float Q = pq[wcc * 128 + rest] + pq[(2 + wcc) * 128 + rest];
            statS[(size_t)(statBase + mt) * 2048 + n0 + c] = S;
            statS[(size_t)(statBase + mt) * 2048 + 1024 + n0 + c] = Q;
        }
    }
}

// ---------------- BN reduce + coef ----------------
__global__ __launch_bounds__(256) void bnreduce_kernel(const float* __restrict__ scratch, int T,
                                                       const float* __restrict__ g, const float* __restrict__ be,
                                                       float* __restrict__ coef) {
    int c = blockIdx.x * 256 + threadIdx.x;  // [0, 1024)
    float S = 0.f, Q = 0.f;
    for (int t = 0; t < T; ++t) {
        S += scratch[(size_t)t * 2048 + c];
        Q += scratch[(size_t)t * 2048 + 1024 + c];
    }
    float m = S / (float)N_NODES;
    float v = Q / (float)N_NODES - m * m;
    float sc = g[c] * rsqrtf(v + 1e-5f);
    coef[c] = sc;
    coef[HID + c] = be[c] - m * sc;
}

__global__ __launch_bounds__(256) void bnapply_kernel(f16* __restrict__ X, const float* __restrict__ coef) {
    int idx = blockIdx.x * 256 + threadIdx.x;  // real rows only: grid = N_NODES*128/256
    int c8 = idx & 127;
    f16x8 v = *(const f16x8*)(X + (size_t)idx * 8);
    float4 sc0 = ((const float4*)coef)[c8 * 2];
    float4 sc1 = ((const float4*)coef)[c8 * 2 + 1];
    float4 sh0 = ((const float4*)(coef + HID))[c8 * 2];
    float4 sh1 = ((const float4*)(coef + HID))[c8 * 2 + 1];
    float y[8];
    y[0] = (float)v[0] * sc0.x + sh0.x; y[1] = (float)v[1] * sc0.y + sh0.y;
    y[2] = (float)v[2] * sc0.z + sh0.z; y[3] = (float)v[3] * sc0.w + sh0.w;
    y[4] = (float)v[4] * sc1.x + sh1.x; y[5] = (float)v[5] * sc1.y + sh1.y;
    y[6] = (float)v[6] * sc1.z + sh1.z; y[7] = (float)v[7] * sc1.w + sh1.w;
    f16x8 o;
#pragma unroll
    for (int j = 0; j < 8; j++) o[j] = (f16)(y[j] > 0.f ? y[j] : 0.f);
    *(f16x8*)(X + (size_t)idx * 8) = o;
}

// ---------------- final fc: out[50000,10] = h3 @ Wo + bo ----------------
__global__ __launch_bounds__(256) void fcout_kernel(const f16* __restrict__ h3, const float* __restrict__ Wo,
                                                    const float* __restrict__ bo, float* __restrict__ out) {
    __shared__ float wos[F_MID * F_OUT];
    for (int i = threadIdx.x; i < F_MID * F_OUT; i += 256) wos[i] = Wo[i];
    __syncthreads();
    int wave = threadIdx.x >> 6, lane = threadIdx.x & 63;
    int node = blockIdx.x * 4 + wave;
    f16x8 v = *(const f16x8*)(h3 + (size_t)node * F_MID + lane * 8);
    float acc[F_OUT];
#pragma unroll
    for (int o = 0; o < F_OUT; o++) acc[o] = 0.f;
#pragma unroll
    for (int j = 0; j < 8; j++) {
        float a = (float)v[j];
        const float* wr = &wos[(lane * 8 + j) * F_OUT];
#pragma unroll
        for (int o = 0; o < F_OUT; o++) acc[o] += a * wr[o];
    }
#pragma unroll
    for (int o = 0; o < F_OUT; o++) {
#pragma unroll
        for (int s = 32; s > 0; s >>= 1) acc[o] += __shfl_down(acc[o], s);
    }
    if (lane == 0) {
#pragma unroll
        for (int o = 0; o < F_OUT; o++) out[(size_t)node * F_OUT + o] = acc[o] + bo[o];
    }
}

extern "C" void kernel_launch(void* const* d_in, const int* in_sizes, int n_in,
                              void* d_out, int out_size, void* d_ws, size_t ws_size,
                              hipStream_t stream) {
    const float* x   = (const float*)d_in[0];
    const int*   edge= (const int*)d_in[1];
    const float* W1l = (const float*)d_in[2];
    const float* W1r = (const float*)d_in[4];
    const float* g1  = (const float*)d_in[5];
    const float* be1 = (const float*)d_in[6];
    const float* W2l = (const float*)d_in[7];
    const float* W2r = (const float*)d_in[9];
    const float* g2  = (const float*)d_in[10];
    const float* be2 = (const float*)d_in[11];
    const float* Wf  = (const float*)d_in[12];
    const float* bf  = (const float*)d_in[13];
    const float* Wo  = (const float*)d_in[14];
    const float* bo  = (const float*)d_in[15];
    float* out = (float*)d_out;

    // b1, b2 unused: per-column constant shift before training-mode BN is a mathematical no-op.

    char* w = (char*)d_ws;
    size_t off = 0;
    auto alloc = [&](size_t bytes) -> void* {
        void* p = w + off;
        off = (off + bytes + 255) & ~(size_t)255;
        return p;
    };
    int* rowptr = (int*)alloc((size_t)(2 * N_NODES + 1) * 4);
    int* cursor = rowptr + (N_NODES + 1);
    int* col    = (int*)alloc((size_t)N_EDGES * 4);
    int* bsums  = (int*)alloc(4096);
    f16* W1lt   = (f16*)alloc((size_t)HID * F_IN * 2);
    f16* W1rt   = (f16*)alloc((size_t)HID * F_IN * 2);
    f16* W2lt   = (f16*)alloc((size_t)HID * HID * 2);
    f16* W2rt   = (f16*)alloc((size_t)HID * HID * 2);
    f16* Wft    = (f16*)alloc((size_t)F_MID * HID * 2);
    float* coef = (float*)alloc((size_t)2 * HID * 4);
    float* statS= (float*)alloc((size_t)392 * 2048 * 4);   // BN-stats partials [392][2][1024]
    f16* B1     = (f16*)alloc((size_t)MP * HID * 2);       // h1pre -> h1; later h3
    f16* B2     = (f16*)alloc((size_t)MP * HID * 2);       // [xh | agg1h] -> h2pre -> h2
    f16* aggbuf = (f16*)alloc((size_t)CH * HID * 2);

    if (off > ws_size) {
        probe_kernel<<<(out_size + 255) / 256, 256, 0, stream>>>(out, out_size, (float)(ws_size >> 20));
        return;
    }

    f16* xh    = B2;
    f16* agg1h = B2 + (size_t)MP * F_IN;
    f16* hp    = B1;   // h1pre -> h1
    f16* h2p   = B2;   // h2pre -> h2
    f16* h3    = B1;

    const int* src = edge;
    const int* dst = edge + N_EDGES;

    // CSR build
    zero_i32<<<(2 * N_NODES + 1 + 255) / 256, 256, 0, stream>>>(rowptr, 2 * N_NODES + 1);
    hist_kernel<<<(N_EDGES + 255) / 256, 256, 0, stream>>>(dst, rowptr);
    const int nScan = N_NODES + 1;
    const int nb = (nScan + 255) / 256;
    scan1_kernel<<<nb, 256, 0, stream>>>(rowptr, bsums, nScan);
    scan2_kernel<<<1, 256, 0, stream>>>(bsums, nb);
    scan3_kernel<<<nb, 256, 0, stream>>>(rowptr, bsums, nScan);
    fill_kernel<<<(N_EDGES + 255) / 256, 256, 0, stream>>>(src, dst, rowptr, cursor, col);

    // weights -> fp16 B^T layout
    transw_all<<<dim3(4, 128, 5), 256, 0, stream>>>(W1l, W1lt, W1r, W1rt, W2l, W2lt, W2r, W2rt, Wf, Wft);

    // layer 1: h1pre = agg1@W1l^T + x@W1r^T   (pad rows zero-filled inside convx/agg1)
    convx_kernel<<<(MP * 64) / 256, 256, 0, stream>>>(x, xh);
    agg1_kernel<<<MP / 4, 256, 0, stream>>>(xh, rowptr, col, agg1h);
    gemm128_f16<<<1568, 256, 0, stream>>>(agg1h, W1lt, F_IN, xh, W1rt, F_IN,
                                          hp, nullptr, statS, 0, HID, 2);      // 392 mt x 4 nt
    bnreduce_kernel<<<4, 256, 0, stream>>>(statS, 392, g1, be1, coef);
    bnapply_kernel<<<(N_NODES * 128) / 256, 256, 0, stream>>>(hp, coef);  // hp := h1 (pad stays 0)

    // layer 2 (M-chunked, 2 chunks of 25088 rows = 196 tiles each)
    for (int c = 0; c < 2; ++c) {
        const int m_base = c * CH;
        const int real = c ? (N_NODES - CH) : CH;  // 24912 / 25088
        agg2_kernel<<<CH / 2, 256, 0, stream>>>(hp, rowptr, col, aggbuf, m_base, real);
        gemm128_f16<<<784, 256, 0, stream>>>(
            aggbuf, W2lt, HID, hp + (size_t)m_base * HID, W2rt, HID,
            h2p + (size_t)m_base * HID, nullptr, statS, c * 196, HID, 2);      // 196 mt x 4 nt
    }
    bnreduce_kernel<<<4, 256, 0, stream>>>(statS, 392, g2, be2, coef);
    bnapply_kernel<<<(N_NODES * 128) / 256, 256, 0, stream>>>(h2p, coef);  // h2p := h2

    // head: h3 = relu(h2@Wf^T + bf); out = h3@Wo + bo
    gemm128_f16<<<784, 256, 0, stream>>>(h2p, Wft, HID, nullptr, nullptr, 0,
                                         h3, bf, nullptr, 0, F_MID, 1);        // 392 mt x 2 nt
    fcout_kernel<<<12500, 256, 0, stream>>>(h3, Wo, bo, out);
}

// Round 11
// 977.193 us; speedup vs baseline: 1.1540x; 1.1540x over previous
//
#include <hip/hip_runtime.h>
#include <hip/hip_bf16.h>
#include <stdint.h>

#define N_NODES 50000
#define N_EDGES 400000
#define F_IN 256
#define HID 1024
#define F_MID 512
#define F_OUT 10
#define MP 50176      // N_NODES padded to 224*224 (= 196*256 too)
#define CH 25088      // layer-2 M-chunk (112*224)

typedef _Float16 f16;
typedef _Float16 f16x4 __attribute__((ext_vector_type(4)));
typedef _Float16 f16x8 __attribute__((ext_vector_type(8)));
typedef float f32x4 __attribute__((ext_vector_type(4)));

__device__ static inline void async_load16(const void* g, void* l) {
    __builtin_amdgcn_global_load_lds(
        (const __attribute__((address_space(1))) unsigned int*)(uintptr_t)g,
        (__attribute__((address_space(3))) unsigned int*)(uintptr_t)l, 16, 0, 0);
}

// ---------------- utility ----------------
__global__ __launch_bounds__(256) void zero_i32(int* __restrict__ p, int n) {
    int i = blockIdx.x * 256 + threadIdx.x;
    if (i < n) p[i] = 0;
}

__global__ __launch_bounds__(256) void probe_kernel(float* __restrict__ out, int n, float val) {
    int i = blockIdx.x * 256 + threadIdx.x;
    if (i < n) out[i] = (i == 0) ? val : 0.f;
}

// ---------------- CSR build ----------------
__global__ __launch_bounds__(256) void hist_kernel(const int* __restrict__ dst, int* __restrict__ rowptr) {
    int e = blockIdx.x * 256 + threadIdx.x;
    if (e < N_EDGES) atomicAdd(&rowptr[dst[e] + 1], 1);
}

__global__ __launch_bounds__(256) void scan1_kernel(int* __restrict__ data, int* __restrict__ bsums, int n) {
    __shared__ int tmp[256];
    int idx = blockIdx.x * 256 + threadIdx.x;
    int v = (idx < n) ? data[idx] : 0;
    tmp[threadIdx.x] = v;
    __syncthreads();
    for (int o = 1; o < 256; o <<= 1) {
        int t = (threadIdx.x >= o) ? tmp[threadIdx.x - o] : 0;
        __syncthreads();
        tmp[threadIdx.x] += t;
        __syncthreads();
    }
    if (idx < n) data[idx] = tmp[threadIdx.x];
    if (threadIdx.x == 255) bsums[blockIdx.x] = tmp[255];
}

__global__ __launch_bounds__(256) void scan2_kernel(int* __restrict__ bsums, int nb) {
    __shared__ int tmp[256];
    int t = threadIdx.x;
    int v = (t < nb) ? bsums[t] : 0;
    tmp[t] = v;
    __syncthreads();
    for (int o = 1; o < 256; o <<= 1) {
        int u = (t >= o) ? tmp[t - o] : 0;
        __syncthreads();
        tmp[t] += u;
        __syncthreads();
    }
    if (t < nb) bsums[t] = tmp[t] - v;  // exclusive block offsets
}

__global__ __launch_bounds__(256) void scan3_kernel(int* __restrict__ data, const int* __restrict__ bsums, int n) {
    int idx = blockIdx.x * 256 + threadIdx.x;
    if (idx < n) data[idx] += bsums[blockIdx.x];
}

__global__ __launch_bounds__(256) void fill_kernel(const int* __restrict__ src, const int* __restrict__ dst,
                                                   const int* __restrict__ rowptr, int* __restrict__ cursor,
                                                   int* __restrict__ col) {
    int e = blockIdx.x * 256 + threadIdx.x;
    if (e < N_EDGES) {
        int d = dst[e];
        int p = atomicAdd(&cursor[d], 1);
        col[rowptr[d] + p] = src[e];
    }
}

// ---------------- batched weight transpose fp32 [K][N] -> fp16 [N][K] ----------------
__global__ __launch_bounds__(256) void transw_all(const float* __restrict__ Wa, f16* __restrict__ Ta,
                                                  const float* __restrict__ Wb, f16* __restrict__ Tb,
                                                  const float* __restrict__ Wc, f16* __restrict__ Tc,
                                                  const float* __restrict__ Wd, f16* __restrict__ Td,
                                                  const float* __restrict__ We, f16* __restrict__ Te) {
    const float* W; f16* T; int N, K;
    switch (blockIdx.z) {
        case 0: W = Wa; T = Ta; N = HID;   K = F_IN; break;
        case 1: W = Wb; T = Tb; N = HID;   K = F_IN; break;
        case 2: W = Wc; T = Tc; N = HID;   K = HID;  break;
        case 3: W = Wd; T = Td; N = HID;   K = HID;  break;
        default:W = We; T = Te; N = F_MID; K = HID;  break;
    }
    int n = blockIdx.x * 256 + threadIdx.x;
    int k0 = blockIdx.y * 8;
    if (n >= N || k0 >= K) return;
    f16x8 o;
#pragma unroll
    for (int j = 0; j < 8; j++) o[j] = (f16)W[(size_t)(k0 + j) * N + n];
    *(f16x8*)(T + (size_t)n * K + k0) = o;
}

// ---------------- x fp32 -> fp16 (covers pad rows with zeros) ----------------
__global__ __launch_bounds__(256) void convx_kernel(const float* __restrict__ x, f16* __restrict__ xh) {
    int idx = blockIdx.x * 256 + threadIdx.x;  // MP*64 float4 units
    if (idx < N_NODES * 64) {
        float4 v = ((const float4*)x)[idx];
        f16x4 o;
        o[0] = (f16)v.x; o[1] = (f16)v.y; o[2] = (f16)v.z; o[3] = (f16)v.w;
        *(f16x4*)(xh + (size_t)idx * 4) = o;
    } else {
        *(f16x4*)(xh + (size_t)idx * 4) = (f16x4){};
    }
}

// ---------------- mean aggregation, layer 1 (barrier-free; zero-fills pad rows) ----------------
__global__ __launch_bounds__(256) void agg1_kernel(const f16* __restrict__ xh, const int* __restrict__ rowptr,
                                                   const int* __restrict__ col, f16* __restrict__ agg1h) {
    const int node = blockIdx.x * 4 + (threadIdx.x >> 6);
    const int t = threadIdx.x & 63;
    if (node >= N_NODES) {
        *(f16x4*)(agg1h + (size_t)node * F_IN + t * 4) = (f16x4){};
        return;
    }
    const int beg = rowptr[node], end = rowptr[node + 1];
    float a0 = 0.f, a1 = 0.f, a2 = 0.f, a3 = 0.f;
    int e = beg;
    for (; e + 3 < end; e += 4) {
        int c0 = col[e], c1 = col[e + 1], c2 = col[e + 2], c3 = col[e + 3];
        f16x4 v0 = *(const f16x4*)(xh + (size_t)c0 * F_IN + t * 4);
        f16x4 v1 = *(const f16x4*)(xh + (size_t)c1 * F_IN + t * 4);
        f16x4 v2 = *(const f16x4*)(xh + (size_t)c2 * F_IN + t * 4);
        f16x4 v3 = *(const f16x4*)(xh + (size_t)c3 * F_IN + t * 4);
        a0 += (float)v0[0] + (float)v1[0] + (float)v2[0] + (float)v3[0];
        a1 += (float)v0[1] + (float)v1[1] + (float)v2[1] + (float)v3[1];
        a2 += (float)v0[2] + (float)v1[2] + (float)v2[2] + (float)v3[2];
        a3 += (float)v0[3] + (float)v1[3] + (float)v2[3] + (float)v3[3];
    }
    for (; e < end; ++e) {
        f16x4 v = *(const f16x4*)(xh + (size_t)col[e] * F_IN + t * 4);
        a0 += (float)v[0]; a1 += (float)v[1]; a2 += (float)v[2]; a3 += (float)v[3];
    }
    int deg = end - beg;
    float inv = 1.f / (float)(deg > 1 ? deg : 1);
    f16x4 o;
    o[0] = (f16)(a0 * inv); o[1] = (f16)(a1 * inv);
    o[2] = (f16)(a2 * inv); o[3] = (f16)(a3 * inv);
    *(f16x4*)(agg1h + (size_t)node * F_IN + t * 4) = o;
}

// ---------------- mean aggregation, layer 2 (barrier-free; zero-fills pad rows) ----------------
__global__ __launch_bounds__(256) void agg2_kernel(const f16* __restrict__ h1, const int* __restrict__ rowptr,
                                                   const int* __restrict__ col, f16* __restrict__ aggbuf,
                                                   int m_base, int real) {
    const int local = blockIdx.x * 2 + (threadIdx.x >> 7);
    const int t = threadIdx.x & 127;
    if (local >= real) {
        *(f16x8*)(aggbuf + (size_t)local * HID + t * 8) = (f16x8){};
        return;
    }
    const int node = m_base + local;
    const int beg = rowptr[node], end = rowptr[node + 1];
    float a[8];
#pragma unroll
    for (int j = 0; j < 8; j++) a[j] = 0.f;
    int e = beg;
    for (; e + 3 < end; e += 4) {
        int c0 = col[e], c1 = col[e + 1], c2 = col[e + 2], c3 = col[e + 3];
        f16x8 v0 = *(const f16x8*)(h1 + (size_t)c0 * HID + t * 8);
        f16x8 v1 = *(const f16x8*)(h1 + (size_t)c1 * HID + t * 8);
        f16x8 v2 = *(const f16x8*)(h1 + (size_t)c2 * HID + t * 8);
        f16x8 v3 = *(const f16x8*)(h1 + (size_t)c3 * HID + t * 8);
#pragma unroll
        for (int j = 0; j < 8; j++)
            a[j] += (float)v0[j] + (float)v1[j] + (float)v2[j] + (float)v3[j];
    }
    for (; e < end; ++e) {
        f16x8 v = *(const f16x8*)(h1 + (size_t)col[e] * HID + t * 8);
#pragma unroll
        for (int j = 0; j < 8; j++) a[j] += (float)v[j];
    }
    int deg = end - beg;
    float inv = 1.f / (float)(deg > 1 ? deg : 1);
    f16x8 o;
#pragma unroll
    for (int j = 0; j < 8; j++) o[j] = (f16)(a[j] * inv);
    *(f16x8*)(aggbuf + (size_t)local * HID + t * 8) = o;
}

// ---------------- read-ahead 4-phase 224x256 two-source MFMA GEMM (fused BN stats) --------
// BEST VERIFIED (round 6: L2 124.4 us, MfmaUtil 34.5%, FETCH 84 MB, conflicts 0).
// 512 threads = 8 waves (2M x 4N); accA rows wr*64+mf*16 (mf 0-3, half 0), accB rows
// 128+wr*48+mf*16 (mf 0-2, half 1). READ-AHEAD schedule: each phase's ds_reads are issued
// one phase EARLY, inside the previous MFMA region, so LDS latency drains under MFMA and
// each lgkmcnt(0) finds data ready. ONE raw s_barrier per phase (4/K-tile):
//   region = [SB0; s_barrier; STG; (vmcnt); lgkmcnt(0); SB0; next-phase reads; MFMA]
// WAR: reads of section S complete at the lgkmcnt of the region AFTER their issue-region;
// S is restaged only after the NEXT barrier (STG placed after the barrier). vmcnt(6) once
// per K-tile at P4, before the read-ahead of tile t+1's a0/b0 (exactly what it guarantees).
// Structural note (rounds 2-10): measured time = MFMA-pipe + LDS-pipe + ~400cyc/phase sync
// overhead; six schedules and a 2-block/CU variant all land 31-35% MfmaUtil. This is the
// best of the family; the next tier requires the exact m201 256^2 schedule.
// Output tile 224x256; staging loads full 256-row A-panel (callers give 32 rows slack).
// Grids 448/896 = 87.5% CU pack; XCD-chunked remap + N-fastest decode (FETCH 221->84 MB).
__global__ __launch_bounds__(512, 2) void gemm224_f16(const f16* __restrict__ A0, const f16* __restrict__ B0, int K0,
                                                      const f16* __restrict__ A1, const f16* __restrict__ B1, int K1,
                                                      f16* __restrict__ C, const float* __restrict__ bias,
                                                      float* __restrict__ statS, int statBase, int N, int lnN) {
    __shared__ __align__(16) f16 smem[65536];  // 128 KiB: [buf][A 16K f16 | B 16K f16]
    const int tid = threadIdx.x;
    const int wid = tid >> 6, lane = tid & 63;
    const int wr = wid >> 2, wc = wid & 3;
    const int r16 = lane & 15, q = lane >> 4, sw = lane & 7;
    const int nwg = (int)gridDim.x;
    const int bid = (int)blockIdx.x;
    const int wgid = (bid & 7) * (nwg >> 3) + (bid >> 3);  // XCD-chunked (nwg%8==0)
    const int mt = wgid >> lnN;
    const int nt = wgid & ((1 << lnN) - 1);                // N fastest within chunk
    const int m0 = mt * 224;
    const int n0 = nt << 8;
    const int T0 = K0 >> 6;
    const int T = T0 + (K1 >> 6);

    // one half-tile stage: s: 0=A rows0-127, 1=B rows0-127, 2=A rows128-255, 3=B rows128-255
#define STG(t, s) do {                                                                        \
        const f16* Sb; int kk, KK;                                                            \
        if ((t) < T0) { Sb = ((s) & 1) ? B0 : A0; kk = (t) << 6;        KK = K0; }            \
        else          { Sb = ((s) & 1) ? B1 : A1; kk = ((t) - T0) << 6; KK = K1; }            \
        const int rr0 = ((((s) & 1) ? n0 : m0)) + (((s) & 2) << 6) + (tid >> 3);              \
        const size_t gof = (size_t)rr0 * KK + (kk + (((tid & 7) ^ ((tid >> 3) & 7)) << 3));   \
        f16* dst = &smem[(((t) & 1) << 15) + (((s) & 1) << 14) + (((s) & 2) << 12) +          \
                         ((tid >> 6) << 9)];                                                  \
        async_load16(Sb + gof, dst);                                                          \
        async_load16(Sb + gof + ((size_t)KK << 6), dst + 4096);                               \
    } while (0)

#define RD_A0(SA) _Pragma("unroll") for (int mf = 0; mf < 4; mf++) {                          \
        const f16* p = (SA) + ((wr * 64 + mf * 16 + r16) << 6);                               \
        a0[mf][0] = *(const f16x8*)(p + c0); a0[mf][1] = *(const f16x8*)(p + c1); }
#define RD_A1(SA) _Pragma("unroll") for (int mf = 0; mf < 3; mf++) {                          \
        const f16* p = (SA) + ((128 + wr * 48 + mf * 16 + r16) << 6);                         \
        a1[mf][0] = *(const f16x8*)(p + c0); a1[mf][1] = *(const f16x8*)(p + c1); }
#define RD_B0(SB) _Pragma("unroll") for (int nf = 0; nf < 2; nf++) {                          \
        const f16* p = (SB) + ((wc * 32 + nf * 16 + r16) << 6);                               \
        b0f[nf][0] = *(const f16x8*)(p + c0); b0f[nf][1] = *(const f16x8*)(p + c1); }
#define RD_B1(SB) _Pragma("unroll") for (int nf = 0; nf < 2; nf++) {                          \
        const f16* p = (SB) + ((128 + wc * 32 + nf * 16 + r16) << 6);                         \
        b1f[nf][0] = *(const f16x8*)(p + c0); b1f[nf][1] = *(const f16x8*)(p + c1); }

    // k-chunk outer: each acc reused only after NM*2 independent MFMAs (dep-latency hidden)
#define MM(ACC, NH, AF, BF, NM)                                                               \
    _Pragma("unroll") for (int kc_ = 0; kc_ < 2; kc_++)                                       \
    _Pragma("unroll") for (int mf_ = 0; mf_ < NM; mf_++)                                      \
    _Pragma("unroll") for (int nf_ = 0; nf_ < 2; nf_++)                                       \
        ACC[mf_][NH][nf_] = __builtin_amdgcn_mfma_f32_16x16x32_f16(AF[mf_][kc_], BF[nf_][kc_],\
                                                                   ACC[mf_][NH][nf_], 0, 0, 0);

#define SB0 __builtin_amdgcn_sched_barrier(0)
#define BAR asm volatile("s_barrier")
#define WLG asm volatile("s_waitcnt lgkmcnt(0)")

    f32x4 accA[4][2][2];  // [mf 0-3][nh][nf]  rows wr*64 + mf*16        (half 0: 0-127)
    f32x4 accB[3][2][2];  // [mf 0-2][nh][nf]  rows 128 + wr*48 + mf*16  (half 1: 128-223)
#pragma unroll
    for (int a = 0; a < 4; a++)
#pragma unroll
        for (int b = 0; b < 2; b++)
#pragma unroll
            for (int c = 0; c < 2; c++) accA[a][b][c] = (f32x4){0.f, 0.f, 0.f, 0.f};
#pragma unroll
    for (int a = 0; a < 3; a++)
#pragma unroll
        for (int b = 0; b < 2; b++)
#pragma unroll
            for (int c = 0; c < 2; c++) accB[a][b][c] = (f32x4){0.f, 0.f, 0.f, 0.f};

    const int c0 = (q ^ sw) << 3;        // swizzled k-chunk offsets (f16 units)
    const int c1 = ((4 + q) ^ sw) << 3;

    f16x8 a0[4][2], a1[3][2], b0f[2][2], b1f[2][2];

    // prologue: tile0 fully + tile1 s0..s2; vmcnt(6) -> tile0's 8 loads landed
    STG(0, 0); STG(0, 1); STG(0, 2); STG(0, 3);
    if (T > 1) {
        STG(1, 0); STG(1, 1); STG(1, 2);
        asm volatile("s_waitcnt vmcnt(6)");
    } else {
        asm volatile("s_waitcnt vmcnt(0)");
    }
    BAR;
    RD_A0(smem); RD_B0(smem + 16384);    // tile 0 a0/b0f (waited at P1's lgkmcnt)

    for (int t = 0; t < T; ++t) {
        const f16* sA  = smem + ((t & 1) << 15);
        const f16* sB  = sA + 16384;
        const f16* sA2 = smem + (((t + 1) & 1) << 15);   // next-tile buffer
        const f16* sB2 = sA2 + 16384;
        // === P1: wait a0/b0f; read-ahead b1f(t); MFMA accA-h0 ===
        SB0; BAR;
        if (t + 1 < T) STG(t + 1, 3);
        WLG; SB0;
        RD_B1(sB);
        __builtin_amdgcn_s_setprio(1);
        MM(accA, 0, a0, b0f, 4);
        __builtin_amdgcn_s_setprio(0);
        // === P2: wait b1f; read-ahead a1(t); MFMA accA-h1 ===
        SB0; BAR;
        if (t + 2 < T) STG(t + 2, 0);
        WLG; SB0;
        RD_A1(sA);
        __builtin_amdgcn_s_setprio(1);
        MM(accA, 1, a0, b1f, 4);
        __builtin_amdgcn_s_setprio(0);
        // === P3: wait a1; MFMA accB-h0 (no reads this region) ===
        SB0; BAR;
        if (t + 2 < T) STG(t + 2, 1);
        WLG; SB0;
        __builtin_amdgcn_s_setprio(1);
        MM(accB, 0, a1, b0f, 3);
        __builtin_amdgcn_s_setprio(0);
        // === P4: counted vmcnt; read-ahead a0/b0f(t+1); MFMA accB-h1 ===
        SB0; BAR;
        if (t + 2 < T) {
            STG(t + 2, 2);
            asm volatile("s_waitcnt vmcnt(6)");
        } else {
            asm volatile("s_waitcnt vmcnt(0)");
        }
        WLG; SB0;
        if (t + 1 < T) { RD_A0(sA2); RD_B0(sB2); }
        __builtin_amdgcn_s_setprio(1);
        MM(accB, 1, a1, b1f, 3);
        __builtin_amdgcn_s_setprio(0);
    }
    SB0;
    asm volatile("s_waitcnt lgkmcnt(0)");
#undef STG
#undef RD_A0
#undef RD_A1
#undef RD_B0
#undef RD_B1
#undef MM
#undef SB0
#undef BAR
#undef WLG

    // epilogue: C = acc (+bias, relu). Rows m0..m0+223 (padded, no guard).
#pragma unroll
    for (int mf = 0; mf < 4; mf++)
#pragma unroll
        for (int rr = 0; rr < 4; rr++) {
            const int grow = m0 + wr * 64 + mf * 16 + q * 4 + rr;
            f16* crow = C + (size_t)grow * N + n0;
#pragma unroll
            for (int nh = 0; nh < 2; nh++)
#pragma unroll
                for (int nf = 0; nf < 2; nf++) {
                    const int col = nh * 128 + wc * 32 + nf * 16 + r16;
                    float v = accA[mf][nh][nf][rr];
                    if (bias) { v += bias[n0 + col]; v = v > 0.f ? v : 0.f; }
                    crow[col] = (f16)v;
                }
        }
#pragma unroll
    for (int mf = 0; mf < 3; mf++)
#pragma unroll
        for (int rr = 0; rr < 4; rr++) {
            const int grow = m0 + 128 + wr * 48 + mf * 16 + q * 4 + rr;
            f16* crow = C + (size_t)grow * N + n0;
#pragma unroll
            for (int nh = 0; nh < 2; nh++)
#pragma unroll
                for (int nf = 0; nf < 2; nf++) {
                    const int col = nh * 128 + wc * 32 + nf * 16 + r16;
                    float v = accB[mf][nh][nf][rr];
                    if (bias) { v += bias[n0 + col]; v = v > 0.f ? v : 0.f; }
                    crow[col] = (f16)v;
                }
        }

    // fused BN stats: per-block column sums of its 224x256 C-tile -> statS[statBase+mt][2][1024]
    // (row-mapping-agnostic: accA+accB cover each of the 224 tile rows exactly once)
    if (statS) {
        __syncthreads();  // all waves done with LDS tile reads
        float* ps = (float*)smem;        // 512 floats
        float* pq = ps + 512;
#pragma unroll
        for (int g = 0; g < 4; g++) {    // g = nh*2+nf
            const int nh = g >> 1, nf = g & 1;
            float s = 0.f, qq = 0.f;
#pragma unroll
            for (int mf = 0; mf < 4; mf++)
#pragma unroll
                for (int rr = 0; rr < 4; rr++) { float v = accA[mf][nh][nf][rr]; s += v; qq += v * v; }
#pragma unroll
            for (int mf = 0; mf < 3; mf++)
#pragma unroll
                for (int rr = 0; rr < 4; rr++) { float v = accB[mf][nh][nf][rr]; s += v; qq += v * v; }
            s += __shfl_xor(s, 16); s += __shfl_xor(s, 32);
            qq += __shfl_xor(qq, 16); qq += __shfl_xor(qq, 32);
            if (q == 0) { ps[wid * 64 + g * 16 + r16] = s; pq[wid * 64 + g * 16 + r16] = qq; }
        }
        __syncthreads();
        if (tid < 256) {
            const int c = tid;  // col within 256-wide tile
            const int wcc = (c >> 5) & 3;
            const int g = ((c >> 7) << 1) | ((c >> 4) & 1);
            const int rl = c & 15;
            float S = ps[wcc * 64 + g * 16 + rl] + ps[(4 + wcc) * 64 + g * 16 + rl];
            float Q = pq[wcc * 64 + g * 16 + rl] + pq[(4 + wcc) * 64 + g * 16 + rl];
            statS[(size_t)(statBase + mt) * 2048 + n0 + c] = S;
            statS[(size_t)(statBase + mt) * 2048 + 1024 + n0 + c] = Q;
        }
    }
}

// ---------------- BN reduce + coef ----------------
__global__ __launch_bounds__(256) void bnreduce_kernel(const float* __restrict__ scratch, int T,
                                                       const float* __restrict__ g, const float* __restrict__ be,
                                                       float* __restrict__ coef) {
    int c = blockIdx.x * 256 + threadIdx.x;  // [0, 1024)
    float S = 0.f, Q = 0.f;
    for (int t = 0; t < T; ++t) {
        S += scratch[(size_t)t * 2048 + c];
        Q += scratch[(size_t)t * 2048 + 1024 + c];
    }
    float m = S / (float)N_NODES;
    float v = Q / (float)N_NODES - m * m;
    float sc = g[c] * rsqrtf(v + 1e-5f);
    coef[c] = sc;
    coef[HID + c] = be[c] - m * sc;
}

__global__ __launch_bounds__(256) void bnapply_kernel(f16* __restrict__ X, const float* __restrict__ coef) {
    int idx = blockIdx.x * 256 + threadIdx.x;  // real rows only: grid = N_NODES*128/256
    int c8 = idx & 127;
    f16x8 v = *(const f16x8*)(X + (size_t)idx * 8);
    float4 sc0 = ((const float4*)coef)[c8 * 2];
    float4 sc1 = ((const float4*)coef)[c8 * 2 + 1];
    float4 sh0 = ((const float4*)(coef + HID))[c8 * 2];
    float4 sh1 = ((const float4*)(coef + HID))[c8 * 2 + 1];
    float y[8];
    y[0] = (float)v[0] * sc0.x + sh0.x; y[1] = (float)v[1] * sc0.y + sh0.y;
    y[2] = (float)v[2] * sc0.z + sh0.z; y[3] = (float)v[3] * sc0.w + sh0.w;
    y[4] = (float)v[4] * sc1.x + sh1.x; y[5] = (float)v[5] * sc1.y + sh1.y;
    y[6] = (float)v[6] * sc1.z + sh1.z; y[7] = (float)v[7] * sc1.w + sh1.w;
    f16x8 o;
#pragma unroll
    for (int j = 0; j < 8; j++) o[j] = (f16)(y[j] > 0.f ? y[j] : 0.f);
    *(f16x8*)(X + (size_t)idx * 8) = o;
}

// ---------------- final fc: out[50000,10] = h3 @ Wo + bo ----------------
__global__ __launch_bounds__(256) void fcout_kernel(const f16* __restrict__ h3, const float* __restrict__ Wo,
                                                    const float* __restrict__ bo, float* __restrict__ out) {
    __shared__ float wos[F_MID * F_OUT];
    for (int i = threadIdx.x; i < F_MID * F_OUT; i += 256) wos[i] = Wo[i];
    __syncthreads();
    int wave = threadIdx.x >> 6, lane = threadIdx.x & 63;
    int node = blockIdx.x * 4 + wave;
    f16x8 v = *(const f16x8*)(h3 + (size_t)node * F_MID + lane * 8);
    float acc[F_OUT];
#pragma unroll
    for (int o = 0; o < F_OUT; o++) acc[o] = 0.f;
#pragma unroll
    for (int j = 0; j < 8; j++) {
        float a = (float)v[j];
        const float* wr = &wos[(lane * 8 + j) * F_OUT];
#pragma unroll
        for (int o = 0; o < F_OUT; o++) acc[o] += a * wr[o];
    }
#pragma unroll
    for (int o = 0; o < F_OUT; o++) {
#pragma unroll
        for (int s = 32; s > 0; s >>= 1) acc[o] += __shfl_down(acc[o], s);
    }
    if (lane == 0) {
#pragma unroll
        for (int o = 0; o < F_OUT; o++) out[(size_t)node * F_OUT + o] = acc[o] + bo[o];
    }
}

extern "C" void kernel_launch(void* const* d_in, const int* in_sizes, int n_in,
                              void* d_out, int out_size, void* d_ws, size_t ws_size,
                              hipStream_t stream) {
    const float* x   = (const float*)d_in[0];
    const int*   edge= (const int*)d_in[1];
    const float* W1l = (const float*)d_in[2];
    const float* W1r = (const float*)d_in[4];
    const float* g1  = (const float*)d_in[5];
    const float* be1 = (const float*)d_in[6];
    const float* W2l = (const float*)d_in[7];
    const float* W2r = (const float*)d_in[9];
    const float* g2  = (const float*)d_in[10];
    const float* be2 = (const float*)d_in[11];
    const float* Wf  = (const float*)d_in[12];
    const float* bf  = (const float*)d_in[13];
    const float* Wo  = (const float*)d_in[14];
    const float* bo  = (const float*)d_in[15];
    float* out = (float*)d_out;

    // b1, b2 unused: per-column constant shift before training-mode BN is a mathematical no-op.

    char* w = (char*)d_ws;
    size_t off = 0;
    auto alloc = [&](size_t bytes) -> void* {
        void* p = w + off;
        off = (off + bytes + 255) & ~(size_t)255;
        return p;
    };
    int* rowptr = (int*)alloc((size_t)(2 * N_NODES + 1) * 4);
    int* cursor = rowptr + (N_NODES + 1);
    int* col    = (int*)alloc((size_t)N_EDGES * 4);
    int* bsums  = (int*)alloc(4096);
    f16* W1lt   = (f16*)alloc((size_t)HID * F_IN * 2);
    f16* W1rt   = (f16*)alloc((size_t)HID * F_IN * 2);
    f16* W2lt   = (f16*)alloc((size_t)HID * HID * 2);
    f16* W2rt   = (f16*)alloc((size_t)HID * HID * 2);
    f16* Wft    = (f16*)alloc((size_t)F_MID * HID * 2);
    float* coef = (float*)alloc((size_t)2 * HID * 4);
    float* statS= (float*)alloc((size_t)224 * 2048 * 4);   // BN-stats partials [224][2][1024]
    f16* B1     = (f16*)alloc((size_t)MP * HID * 2);       // h1pre -> h1; later h3
    f16* B2     = (f16*)alloc((size_t)MP * HID * 2);       // [xh | agg1h] -> h2pre -> h2
    f16* aggbuf = (f16*)alloc((size_t)(CH + 32) * HID * 2);// +32 rows staging slack (last tile)

    if (off > ws_size) {
        probe_kernel<<<(out_size + 255) / 256, 256, 0, stream>>>(out, out_size, (float)(ws_size >> 20));
        return;
    }

    f16* xh    = B2;
    f16* agg1h = B2 + (size_t)MP * F_IN;
    f16* hp    = B1;   // h1pre -> h1
    f16* h2p   = B2;   // h2pre -> h2
    f16* h3    = B1;

    const int* src = edge;
    const int* dst = edge + N_EDGES;

    // CSR build
    zero_i32<<<(2 * N_NODES + 1 + 255) / 256, 256, 0, stream>>>(rowptr, 2 * N_NODES + 1);
    hist_kernel<<<(N_EDGES + 255) / 256, 256, 0, stream>>>(dst, rowptr);
    const int nScan = N_NODES + 1;
    const int nb = (nScan + 255) / 256;
    scan1_kernel<<<nb, 256, 0, stream>>>(rowptr, bsums, nScan);
    scan2_kernel<<<1, 256, 0, stream>>>(bsums, nb);
    scan3_kernel<<<nb, 256, 0, stream>>>(rowptr, bsums, nScan);
    fill_kernel<<<(N_EDGES + 255) / 256, 256, 0, stream>>>(src, dst, rowptr, cursor, col);

    // weights -> fp16 B^T layout
    transw_all<<<dim3(4, 128, 5), 256, 0, stream>>>(W1l, W1lt, W1r, W1rt, W2l, W2lt, W2r, W2rt, Wf, Wft);

    // layer 1: h1pre = agg1@W1l^T + x@W1r^T   (pad rows zero-filled inside convx/agg1)
    convx_kernel<<<(MP * 64) / 256, 256, 0, stream>>>(x, xh);
    agg1_kernel<<<MP / 4, 256, 0, stream>>>(xh, rowptr, col, agg1h);
    gemm224_f16<<<896, 512, 0, stream>>>(agg1h, W1lt, F_IN, xh, W1rt, F_IN,
                                         hp, nullptr, statS, 0, HID, 2);       // 224 mt x 4 nt
    bnreduce_kernel<<<4, 256, 0, stream>>>(statS, 224, g1, be1, coef);
    bnapply_kernel<<<(N_NODES * 128) / 256, 256, 0, stream>>>(hp, coef);  // hp := h1 (pad stays 0)

    // layer 2 (M-chunked, 2 chunks of 25088 rows = 112 tiles each)
    for (int c = 0; c < 2; ++c) {
        const int m_base = c * CH;
        const int real = c ? (N_NODES - CH) : CH;  // 24912 / 25088
        agg2_kernel<<<CH / 2, 256, 0, stream>>>(hp, rowptr, col, aggbuf, m_base, real);
        gemm224_f16<<<448, 512, 0, stream>>>(
            aggbuf, W2lt, HID, hp + (size_t)m_base * HID, W2rt, HID,
            h2p + (size_t)m_base * HID, nullptr, statS, c * 112, HID, 2);      // 112 mt x 4 nt
    }
    bnreduce_kernel<<<4, 256, 0, stream>>>(statS, 224, g2, be2, coef);
    bnapply_kernel<<<(N_NODES * 128) / 256, 256, 0, stream>>>(h2p, coef);  // h2p := h2

    // head: h3 = relu(h2@Wf^T + bf); out = h3@Wo + bo
    gemm224_f16<<<448, 512, 0, stream>>>(h2p, Wft, HID, nullptr, nullptr, 0,
                                         h3, bf, nullptr, 0, F_MID, 1);        // 224 mt x 2 nt
    fcout_kernel<<<12500, 256, 0, stream>>>(h3, Wo, bo, out);
}